// Round 1
// baseline (277.784 us; speedup 1.0000x reference)
//
#include <hip/hip_runtime.h>
#include <math.h>

// Problem constants: B=32, H=1024, W=1024, N=100000
#define RD_H 1024
#define RD_W 1024
#define RD_N 100000
#define BDIM 256
#define PTS_PER_THREAD 2                      // window-narrowing: 512 pts/block
#define PTS_PER_BLK (BDIM * PTS_PER_THREAD)   // 512
#define NXCD 8
#define IMGS_PER_XCD 4                        // 32 images / 8 XCDs
#define BLKS_PER_IMG 196                      // ceil(100000 / 512)
#define IMG_PIX (RD_H * RD_W)                 // 1,048,576 floats = 4 MB
#define IMG_F4  (IMG_PIX / 4)                 // 262,144 float4
#define WARM_STRIDE 1338                      // ceil(IMG_F4 / BLKS_PER_IMG)
#define WARM_CALLS 6                          // 6*256 = 1536 >= 1338 (full cover w/ overlap)

__global__ void rd_zero_kernel(float* out) { out[0] = 0.0f; }

typedef __attribute__((address_space(3))) void lds_void;
typedef const __attribute__((address_space(1))) void gbl_void;

__device__ __forceinline__ float rd_term(float za, float zb, int od) {
    float diff = za - zb;
    float gt   = (float)(od - 1);        // {-1, 0, 1}
    float mask = fabsf(gt);              // {0, 1}
    // stable softplus(-gt*diff) = max(x,0) + log1p(exp(-|x|))
    float x  = -gt * diff;
    float sp = fmaxf(x, 0.0f) + log1pf(__expf(-fabsf(x)));
    return mask * sp + (1.0f - mask) * diff * diff;
}

__global__ __launch_bounds__(BDIM) void rd_loss_kernel(
    const float* __restrict__ depth,   // (B, H, W) fp32
    const int*   __restrict__ xA,
    const int*   __restrict__ yA,
    const int*   __restrict__ xB,
    const int*   __restrict__ yB,
    const int*   __restrict__ ord,
    float* __restrict__ out,
    float inv_total)
{
    // LDS-pad to 36 KB -> 4 blocks/CU (16 waves). Resident window per XCD:
    // 4 blk/CU * 32 CU * 512 pts = 65K points = 0.65 image -> the 4 MB L2
    // holds the CURRENT image instead of thrashing across 2+ images.
    __shared__ struct {
        float wsum[BDIM / 64];
        __align__(16) char warmdst[1024];       // throwaway global_load_lds dest
        char occ_pad[36864 - 1024 - 4 * (BDIM / 64)];
    } sm;

    const int tid = threadIdx.x;
    // blockIdx % 8 -> XCD. XCD x owns images [4x, 4x+4); within an XCD,
    // k ascends in dispatch order, so an image's warm + gather blocks are
    // temporally clustered on one XCD's L2.
    const int xcd = blockIdx.x & (NXCD - 1);
    const int k   = blockIdx.x / NXCD;            // 0..783 per XCD, time-ordered
    const int img = xcd * IMGS_PER_XCD + k / BLKS_PER_IMG;
    const int blk = k % BLKS_PER_IMG;

    const float* __restrict__ imgp = depth + (long)img * IMG_PIX;

    const int  n      = blk * PTS_PER_BLK + tid * PTS_PER_THREAD;
    const bool activ  = (n < RD_N);               // tail block of each image
    const long i0     = (long)img * RD_N + n;

    // --- streaming index loads: non-temporal (no L2 allocate) so the 64 MB
    // index stream doesn't evict the warmed depth image. 8 B/lane, coalesced.
    unsigned long long vxa = 0, vya = 0, vxb = 0, vyb = 0, vod = 0;
    if (activ) {
        vxa = __builtin_nontemporal_load((const unsigned long long*)(xA + i0));
        vya = __builtin_nontemporal_load((const unsigned long long*)(yA + i0));
        vxb = __builtin_nontemporal_load((const unsigned long long*)(xB + i0));
        vyb = __builtin_nontemporal_load((const unsigned long long*)(yB + i0));
        vod = __builtin_nontemporal_load((const unsigned long long*)(ord + i0));
    }

    // --- fire-and-forget L2 warm: stream this block's ~21 KB image slice
    // through L2 into a throwaway LDS buffer. Never waited on, never read
    // (racing writes are harmless). Converts the compulsory random 64B depth
    // fetch into a sequential stream; gathers then hit L2.
    {
        const float4* img4 = (const float4*)imgp;
        const int base = blk * WARM_STRIDE;
        #pragma unroll
        for (int c = 0; c < WARM_CALLS; ++c) {
            int w = base + c * BDIM + tid;
            if (w > IMG_F4 - 1) w = IMG_F4 - 1;   // clamp: redundant warm, no OOB
            __builtin_amdgcn_global_load_lds((gbl_void*)(img4 + w),
                                             (lds_void*)sm.warmdst, 16, 0, 0);
        }
    }

    float loss = 0.0f;
    if (activ) {
        const int xa0 = (int)(unsigned)vxa, xa1 = (int)(vxa >> 32);
        const int ya0 = (int)(unsigned)vya, ya1 = (int)(vya >> 32);
        const int xb0 = (int)(unsigned)vxb, xb1 = (int)(vxb >> 32);
        const int yb0 = (int)(unsigned)vyb, yb1 = (int)(vyb >> 32);
        const int od0 = (int)(unsigned)vod, od1 = (int)(vod >> 32);

        // all 4 gathers issued before any use
        const float za0 = imgp[ya0 * RD_W + xa0];
        const float za1 = imgp[ya1 * RD_W + xa1];
        const float zb0 = imgp[yb0 * RD_W + xb0];
        const float zb1 = imgp[yb1 * RD_W + xb1];

        loss = rd_term(za0, zb0, od0) + rd_term(za1, zb1, od1);
    }

    // wave-64 shuffle reduction
    #pragma unroll
    for (int off = 32; off > 0; off >>= 1)
        loss += __shfl_down(loss, off, 64);

    const int lane = threadIdx.x & 63;
    const int wid  = threadIdx.x >> 6;
    if (lane == 0) sm.wsum[wid] = loss;
    __syncthreads();

    if (threadIdx.x == 0) {
        float s = 0.0f;
        #pragma unroll
        for (int w = 0; w < BDIM / 64; ++w) s += sm.wsum[w];
        atomicAdd(out, s * inv_total);   // pre-scaled partial: sum stays O(1)
    }
}

extern "C" void kernel_launch(void* const* d_in, const int* in_sizes, int n_in,
                              void* d_out, int out_size, void* d_ws, size_t ws_size,
                              hipStream_t stream) {
    const float* depth = (const float*)d_in[0];
    const int*   xA    = (const int*)d_in[1];
    const int*   yA    = (const int*)d_in[2];
    const int*   xB    = (const int*)d_in[3];
    const int*   yB    = (const int*)d_in[4];
    const int*   ord   = (const int*)d_in[5];
    float* out = (float*)d_out;

    int total = in_sizes[1];                 // B*N = 3,200,000
    float inv_total = 1.0f / (float)total;

    // d_out is poisoned before every timed launch — zero it first.
    rd_zero_kernel<<<1, 1, 0, stream>>>(out);

    rd_loss_kernel<<<NXCD * IMGS_PER_XCD * BLKS_PER_IMG, BDIM, 0, stream>>>( // 6272 blocks
        depth, xA, yA, xB, yB, ord, out, inv_total);
}